// Round 2
// baseline (532.804 us; speedup 1.0000x reference)
//
#include <hip/hip_runtime.h>

#define NB 4
#define CB 64
#define HB 256
#define WB 256
#define OB 18
#define HWB (HB*WB)
#define TILE 16
#define ICC 8
#define EPSV 1e-5f

__device__ __forceinline__ int reflect_idx(int i, int n) {
    if (i < 0) i = -i;
    if (i >= n) i = 2*n - 2 - i;
    return i;
}

// Async global->LDS DMA, 4 bytes/lane. LDS dst is wave-uniform base + lane*4;
// tile[tid + i*256] satisfies that exactly.
__device__ __forceinline__ void ldsdma4(const float* g, float* l) {
    __builtin_amdgcn_global_load_lds(
        (__attribute__((address_space(1))) unsigned int*)g,
        (__attribute__((address_space(3))) unsigned int*)l, 4, 0, 0);
}

// Transpose weights (18,64,3,3) -> wt[c][o][k]: per channel, the 18 o-slices of
// 9 taps are contiguous, so a wave's o-subset is one contiguous scalar region.
__global__ __launch_bounds__(256) void transpose_w_kernel(
    const float* __restrict__ w, float* __restrict__ wt)
{
    int i = blockIdx.x * 256 + threadIdx.x;
    if (i < OB*CB*9) {
        int o   = i / (CB*9);
        int rem = i - o*CB*9;
        int c   = rem / 9;
        int k   = rem - c*9;
        wt[c*OB*9 + o*9 + k] = w[i];
    }
}

// Issue the 2592-element halo stage for channel-chunk cb into dst (async DMA).
#define STAGE(dst, cb) do {                                            \
    const float* _yb = ybase + (size_t)(cb)*HWB;                       \
    _Pragma("unroll")                                                  \
    for (int _i = 0; _i < 10; ++_i)                                    \
        ldsdma4(_yb + sofs[_i], (dst) + tid + _i*256);                 \
    if (tid < 32) ldsdma4(_yb + sofs[10], (dst) + tid + 2560);         \
} while (0)

// Load the 3x6 halo window (4 horizontal pixels) for channel slot ii.
// Rows are 18 floats; (row*18 + c0) is always even -> valid float2 loads.
#define LOADV(tl, ii) do {                                             \
    _Pragma("unroll")                                                  \
    for (int _dy = 0; _dy < 3; ++_dy) {                                \
        const float2* _t2 = (const float2*)((tl) + (ii)*324 + (r+_dy)*18 + c0); \
        float2 _a = _t2[0], _b = _t2[1], _c = _t2[2];                  \
        v[_dy][0]=_a.x; v[_dy][1]=_a.y; v[_dy][2]=_b.x;                \
        v[_dy][3]=_b.y; v[_dy][4]=_c.x; v[_dy][5]=_c.y;                \
    }                                                                  \
} while (0)

// Kernel 1: 3x3x64->18 conv + per-block sum/sumsq partials.
// Each lane owns 4 horizontal pixels (wave = whole 16x16 tile); the 4 waves
// split the 18 output channels (5,5,4,4): 4x fewer scalar weight-dwords/FMA.
__global__ __launch_bounds__(256) void conv_stats_kernel(
    const float* __restrict__ y, const float* __restrict__ wt,
    float* __restrict__ sigma, float* __restrict__ psum, float* __restrict__ psq)
{
    __shared__ float tile[2][ICC*324];
    const int tid = threadIdx.x;
    const int lane = tid & 63, wv = tid >> 6;
    const int r  = lane >> 2;          // pixel row 0..15
    const int c0 = (lane & 3) * 4;     // pixel col base 0,4,8,12
    const int o0 = (wv < 2) ? wv*5 : wv*4 + 2;   // 0,5,10,14
    const bool has5 = (wv < 2);
    const int bx = blockIdx.x, by = blockIdx.y, n = blockIdx.z;
    const int h0 = by * TILE, w0 = bx * TILE;

    int sofs[11];
#pragma unroll
    for (int i = 0; i < 11; ++i) {
        int j  = tid + i*256;
        int jj = (j < ICC*324) ? j : 0;
        int c   = jj / 324;
        int rem = jj - c*324;
        int rr  = rem / 18;
        int col = rem - rr*18;
        sofs[i] = c*HWB + reflect_idx(h0 - 1 + rr, HB)*WB + reflect_idx(w0 - 1 + col, WB);
    }

    const float* ybase = y + (size_t)n*CB*HWB;

    float acc[4][5];
#pragma unroll
    for (int j = 0; j < 4; ++j)
#pragma unroll
        for (int oi = 0; oi < 5; ++oi) acc[j][oi] = 0.f;

    STAGE(tile[0], 0);
    __syncthreads();

    int cur = 0;
    for (int cb = 0; cb < CB; cb += ICC) {
        if (cb + ICC < CB) STAGE(tile[cur^1], cb + ICC);
        const float* tl = tile[cur];
#pragma unroll
        for (int ii = 0; ii < ICC; ++ii) {
            float v[3][6];
            LOADV(tl, ii);
            const float* wp = wt + (cb + ii)*162 + o0*9;   // 45 contiguous, uniform
#pragma unroll
            for (int oi = 0; oi < 4; ++oi)
#pragma unroll
                for (int dy = 0; dy < 3; ++dy)
#pragma unroll
                    for (int dx = 0; dx < 3; ++dx) {
                        const float w_ = wp[oi*9 + dy*3 + dx];
#pragma unroll
                        for (int j = 0; j < 4; ++j)
                            acc[j][oi] = fmaf(v[dy][dx+j], w_, acc[j][oi]);
                    }
            if (has5)
#pragma unroll
                for (int dy = 0; dy < 3; ++dy)
#pragma unroll
                    for (int dx = 0; dx < 3; ++dx) {
                        const float w_ = wp[36 + dy*3 + dx];
#pragma unroll
                        for (int j = 0; j < 4; ++j)
                            acc[j][4] = fmaf(v[dy][dx+j], w_, acc[j][4]);
                    }
        }
        __syncthreads();
        cur ^= 1;
    }

    const int qbase = (h0 + r)*WB + w0 + c0;
    const int bid = (n*16 + by)*16 + bx;
#pragma unroll
    for (int oi = 0; oi < 5; ++oi) {
        if (oi == 4 && !has5) break;
        const int o = o0 + oi;
        *(float4*)(sigma + ((size_t)n*OB + o)*HWB + qbase) =
            make_float4(acc[0][oi], acc[1][oi], acc[2][oi], acc[3][oi]);
        float s  = acc[0][oi] + acc[1][oi] + acc[2][oi] + acc[3][oi];
        float s2 = acc[0][oi]*acc[0][oi] + acc[1][oi]*acc[1][oi]
                 + acc[2][oi]*acc[2][oi] + acc[3][oi]*acc[3][oi];
        for (int off = 32; off > 0; off >>= 1) {
            s  += __shfl_down(s,  off, 64);
            s2 += __shfl_down(s2, off, 64);
        }
        if (lane == 0) { psum[o*1024 + bid] = s; psq[o*1024 + bid] = s2; }
    }
}

// Kernel 2: reduce 1024 partials per channel -> fused scale/shift
__global__ __launch_bounds__(256) void stats_kernel(
    const float* __restrict__ psum, const float* __restrict__ psq,
    const float* __restrict__ gamma, const float* __restrict__ beta,
    float* __restrict__ scale, float* __restrict__ shift)
{
    const int o = blockIdx.x;
    const int t = threadIdx.x;
    float s = 0.f, s2 = 0.f;
#pragma unroll
    for (int i = 0; i < 4; ++i) {
        s  += psum[o*1024 + t + i*256];
        s2 += psq [o*1024 + t + i*256];
    }
    for (int off = 32; off > 0; off >>= 1) {
        s  += __shfl_down(s,  off, 64);
        s2 += __shfl_down(s2, off, 64);
    }
    __shared__ float red[8];
    const int lane = t & 63, wv = t >> 6;
    if (lane == 0) { red[wv] = s; red[wv + 4] = s2; }
    __syncthreads();
    if (t == 0) {
        float S  = red[0] + red[1] + red[2] + red[3];
        float SS = red[4] + red[5] + red[6] + red[7];
        const float cnt = (float)(NB * HWB);
        float mean = S / cnt;
        float var  = SS / cnt - mean*mean;
        float sc = gamma[o] * rsqrtf(var + EPSV);
        scale[o] = sc;
        shift[o] = beta[o] - mean * sc;
    }
}

// Kernel 3: normalize + softmax + v_map, then adaptive filter -> out.
// Each lane owns 4 horizontal pixels; the 4 waves split the 64 channels
// (out channel c only needs in channel c's halo) -> ~3x less LDS-pipe traffic,
// float4 global access throughout.
__global__ __launch_bounds__(256) void softmax_apply_kernel(
    const float* __restrict__ y, const float* __restrict__ sigma,
    const float* __restrict__ scale, const float* __restrict__ shift,
    float* __restrict__ out)
{
    __shared__ float tile[2][ICC*324];
    const int tid = threadIdx.x;
    const int lane = tid & 63, wv = tid >> 6;
    const int r  = lane >> 2;
    const int c0 = (lane & 3) * 4;
    const int bx = blockIdx.x, by = blockIdx.y, n = blockIdx.z;
    const int h0 = by * TILE, w0 = bx * TILE;
    const int qbase = (h0 + r)*WB + w0 + c0;

    int sofs[11];
#pragma unroll
    for (int i = 0; i < 11; ++i) {
        int j  = tid + i*256;
        int jj = (j < ICC*324) ? j : 0;
        int c   = jj / 324;
        int rem = jj - c*324;
        int rr  = rem / 18;
        int col = rem - rr*18;
        sofs[i] = c*HWB + reflect_idx(h0 - 1 + rr, HB)*WB + reflect_idx(w0 - 1 + col, WB);
    }

    const float* ybase = y + (size_t)n*CB*HWB;

    STAGE(tile[0], 0);     // async: lands while we do softmax below

    float z[4][18];
#pragma unroll
    for (int o = 0; o < OB; ++o) {
        const float4 sg = *(const float4*)(sigma + ((size_t)n*OB + o)*HWB + qbase);
        const float sc = scale[o], sh = shift[o];
        z[0][o] = fmaf(sg.x, sc, sh);
        z[1][o] = fmaf(sg.y, sc, sh);
        z[2][o] = fmaf(sg.z, sc, sh);
        z[3][o] = fmaf(sg.w, sc, sh);
    }
#pragma unroll
    for (int j = 0; j < 4; ++j) {
        float m = z[j][0];
#pragma unroll
        for (int o = 1; o < OB; ++o) m = fmaxf(m, z[j][o]);
        float sum = 0.f;
#pragma unroll
        for (int o = 0; o < OB; ++o) { z[j][o] = __expf(z[j][o] - m); sum += z[j][o]; }
        const float rs = 1.f / sum;
#pragma unroll
        for (int o = 0; o < OB; ++o) z[j][o] *= rs;
    }

    float* vmap = out + (size_t)NB*CB*HWB;
#pragma unroll
    for (int o = 0; o < OB; ++o)
        *(float4*)(vmap + ((size_t)n*OB + o)*HWB + qbase) =
            make_float4(z[0][o], z[1][o], z[2][o], z[3][o]);

    float* obase = out + (size_t)n*CB*HWB;
    __syncthreads();       // prologue DMA drained

#pragma unroll
    for (int ci = 0; ci < 8; ++ci) {
        const int cb = ci * ICC;
        if (ci < 7) STAGE(tile[(ci&1)^1], cb + ICC);
        const float* tl = tile[ci&1];
        const int g = ci >> 2;                    // (cb+ii)>>5, compile-time
#pragma unroll
        for (int jj = 0; jj < 2; ++jj) {
            const int ii = 2*wv + jj;             // this wave's channel slot
            float v[3][6];
            LOADV(tl, ii);
            float a0 = 0.f, a1 = 0.f, a2 = 0.f, a3 = 0.f;
#pragma unroll
            for (int dy = 0; dy < 3; ++dy)
#pragma unroll
                for (int dx = 0; dx < 3; ++dx) {
                    const int k = g*9 + dy*3 + dx;
                    a0 = fmaf(v[dy][dx+0], z[0][k], a0);
                    a1 = fmaf(v[dy][dx+1], z[1][k], a1);
                    a2 = fmaf(v[dy][dx+2], z[2][k], a2);
                    a3 = fmaf(v[dy][dx+3], z[3][k], a3);
                }
            *(float4*)(obase + (size_t)(cb + ii)*HWB + qbase) =
                make_float4(a0, a1, a2, a3);
        }
        __syncthreads();
    }
}

extern "C" void kernel_launch(void* const* d_in, const int* in_sizes, int n_in,
                              void* d_out, int out_size, void* d_ws, size_t ws_size,
                              hipStream_t stream) {
    const float* y     = (const float*)d_in[0];
    const float* w     = (const float*)d_in[1];
    const float* gamma = (const float*)d_in[2];
    const float* beta  = (const float*)d_in[3];
    float* out = (float*)d_out;

    float* sigma = (float*)d_ws;                 // 4*18*65536 floats
    float* wt    = sigma + (size_t)NB*OB*HWB;    // 10368
    float* psum  = wt + OB*CB*9;                 // 18*1024
    float* psq   = psum + OB*1024;               // 18*1024
    float* scale = psq  + OB*1024;               // 18
    float* shift = scale + OB;                   // 18

    dim3 grid(WB/TILE, HB/TILE, NB);   // (16,16,4)
    dim3 block(256);
    transpose_w_kernel<<<dim3((OB*CB*9 + 255)/256), block, 0, stream>>>(w, wt);
    conv_stats_kernel<<<grid, block, 0, stream>>>(y, wt, sigma, psum, psq);
    stats_kernel<<<dim3(OB), block, 0, stream>>>(psum, psq, gamma, beta, scale, shift);
    softmax_apply_kernel<<<grid, block, 0, stream>>>(y, sigma, scale, shift, out);
}